// Round 4
// baseline (38.297 us; speedup 1.0000x reference)
//
#include <hip/hip_runtime.h>
#include <math.h>

#define NKP 133
#define NROWS (256 * NKP)            // 34048
#define RH_TOTAL (2 * NROWS)         // 68096 row-halves of 512
#define NBLOCKS 2048
#define NWAVES (NBLOCKS * 4)         // 8192
#define KMAIN 8                      // 8*8192 = 65536 row-halves in main loop
#define TAIL_CNT (RH_TOTAL - KMAIN * NWAVES)   // 2560
#define C2P  14.4269504088896f       // 10*log2(e)
#define NK2  0.02251706f             // log2(e) / (2*5.66^2)
#define RAD  16.98f                  // 5.66*3

static __device__ __forceinline__ float fexp2(float x) {
    return __builtin_amdgcn_exp2f(x);
}

__global__ __launch_bounds__(256) void rtmcc_partial_kernel(
    const float* __restrict__ pred,       // [RH_TOTAL][512]
    const float* __restrict__ keypoints,  // [NROWS][3]
    float* __restrict__ partials)         // [NBLOCKS]
{
    const int wave = threadIdx.x >> 6;
    const int lane = threadIdx.x & 63;
    const int wid  = blockIdx.x * 4 + wave;   // 0..8191
    const float c0 = (float)(lane * 8);       // this lane's chunk start index
    __shared__ float lds[4];

    float acc = 0.0f;

// ---- PREP: load keypoints for RH, compute (W,MU), issue predicated bulk loads ----
#define PREP(RH, W, MU, PA, PB, GUARD)                                         \
    {                                                                          \
        if (GUARD) {                                                           \
            const int row_ = (RH) >> 1;                                        \
            const float kx_  = keypoints[row_ * 3 + 0];                        \
            const float ky_  = keypoints[row_ * 3 + 1];                        \
            const float vis_ = keypoints[row_ * 3 + 2];                        \
            const float mux_ = rintf(kx_ * 2.0f);                              \
            const float muy_ = rintf(ky_ * 2.0f);                              \
            const bool oob_ = (mux_ - RAD >= 512.0f) || (muy_ - RAD >= 512.0f) \
                           || (mux_ + RAD + 1.0f < 0.0f)                       \
                           || (muy_ + RAD + 1.0f < 0.0f);                      \
            const bool visible_ = (vis_ >= 0.5f);                              \
            W = (visible_ && oob_) ? 0.0f : vis_;                              \
            MU = ((RH) & 1) ? muy_ : mux_;                                     \
            if (W > 0.0f) {                                                    \
                const float* p_ = pred + (size_t)(RH) * 512 + lane * 8;        \
                PA = *reinterpret_cast<const float4*>(p_);                     \
                PB = *reinterpret_cast<const float4*>(p_ + 4);                 \
            }                                                                  \
        } else { W = 0.0f; }                                                   \
    }

// ---- COMPUTE: bulk exp-sum + register-resident gaussian window + reduce ----
#define COMPUTE(W, MU, PA, PB)                                                 \
    if (W > 0.0f) {                                                            \
        const float pv_[8] = {PA.x, PA.y, PA.z, PA.w, PB.x, PB.y, PB.z, PB.w}; \
        float S = 0.0f, P = 0.0f;                                              \
        _Pragma("unroll")                                                      \
        for (int u = 0; u < 8; ++u) { S += fexp2(C2P * pv_[u]); P += pv_[u]; } \
        float Zw = 0.0f, Tp = 0.0f, Pd = P;                                    \
        if (c0 >= MU - 42.0f && c0 <= MU + 35.0f) {   /* lanes touching window */ \
            _Pragma("unroll")                                                  \
            for (int u = 0; u < 8; ++u) {                                      \
                const float d_ = c0 + (float)u - MU;                           \
                const float g_ = fexp2(d_ * d_ * -NK2);  /* gaussian target */ \
                const float e_ = fexp2(g_ * C2P);        /* exp(10*g) */       \
                const float em1_ = e_ - 1.0f;                                  \
                Zw += em1_;                                                    \
                Tp += e_ * g_;                                                 \
                Pd += em1_ * pv_[u];                                           \
            }                                                                  \
        }                                                                      \
        _Pragma("unroll")                                                      \
        for (int off = 1; off < 64; off <<= 1) {                               \
            S  += __shfl_xor(S,  off, 64);                                     \
            Zw += __shfl_xor(Zw, off, 64);                                     \
            Tp += __shfl_xor(Tp, off, 64);                                     \
            Pd += __shfl_xor(Pd, off, 64);                                     \
        }                                                                      \
        const float Z = 512.0f + Zw;     /* far-field e==1 exactly */          \
        acc += W * (10.0f * (Tp - Pd) / Z + __logf(S) - __logf(Z));            \
    }

    float w0, mu0; float4 a0, b0;
    float w1, mu1; float4 a1, b1;

    PREP(wid, w0, mu0, a0, b0, true);          // prologue: k=0 in flight

    #pragma unroll
    for (int kk = 0; kk < KMAIN; kk += 2) {
        PREP(wid + (kk + 1) * NWAVES, w1, mu1, a1, b1, true);
        COMPUTE(w0, mu0, a0, b0);
        // kk+2 == KMAIN means prefetching the tail row-half (only first 2560 waves)
        PREP(wid + (kk + 2) * NWAVES, w0, mu0, a0, b0,
             (kk + 2 < KMAIN) || (wid < TAIL_CNT));
        COMPUTE(w1, mu1, a1, b1);
    }
    COMPUTE(w0, mu0, a0, b0);                  // tail (w0==0 when absent)

    acc *= (1.0f / (512.0f * 133.0f));
    if (lane == 0) lds[wave] = acc;
    __syncthreads();
    if (threadIdx.x == 0)
        partials[blockIdx.x] = lds[0] + lds[1] + lds[2] + lds[3];
}

__global__ __launch_bounds__(256) void rtmcc_reduce_kernel(
    const float* __restrict__ partials, float* __restrict__ out)
{
    __shared__ float lds[4];
    float s = 0.0f;
    for (int i = threadIdx.x; i < NBLOCKS; i += 256) s += partials[i];
    #pragma unroll
    for (int off = 1; off < 64; off <<= 1) s += __shfl_xor(s, off, 64);
    if ((threadIdx.x & 63) == 0) lds[threadIdx.x >> 6] = s;
    __syncthreads();
    if (threadIdx.x == 0) out[0] = lds[0] + lds[1] + lds[2] + lds[3];
}

extern "C" void kernel_launch(void* const* d_in, const int* in_sizes, int n_in,
                              void* d_out, int out_size, void* d_ws, size_t ws_size,
                              hipStream_t stream) {
    const float* pred = (const float*)d_in[0];   // (256,133,1024) fp32
    const float* kpts = (const float*)d_in[1];   // (256,133,3) fp32
    float* out = (float*)d_out;
    float* partials = (float*)d_ws;

    rtmcc_partial_kernel<<<NBLOCKS, 256, 0, stream>>>(pred, kpts, partials);
    rtmcc_reduce_kernel<<<1, 256, 0, stream>>>(partials, out);
}

// Round 5
// 29.310 us; speedup vs baseline: 1.3066x; 1.3066x over previous
//
#include <hip/hip_runtime.h>
#include <math.h>

#define NKP 133
#define NROWS (256 * NKP)            // 34048
#define RH_TOTAL (2 * NROWS)         // 68096 row-halves of 512
#define NBLOCKS 2048
#define NWAVES (NBLOCKS * 4)         // 8192
#define C2P  14.4269504088896f       // 10*log2(e):  exp(10x) = exp2(C2P*x)
#define NK2  0.02251706f             // log2(e)/(2*5.66^2)
#define RAD  16.98f                  // 5.66*3
#define LN2f 0.69314718055994531f

static __device__ __forceinline__ float fexp2(float x) {
    return __builtin_amdgcn_exp2f(x);
}

__global__ __launch_bounds__(256) void rtmcc_partial_kernel(
    const float* __restrict__ pred,       // [RH_TOTAL][512]
    const float* __restrict__ keypoints,  // [NROWS][3]
    float* __restrict__ partials)         // [NBLOCKS]
{
    const int wave = threadIdx.x >> 6;
    const int lane = threadIdx.x & 63;
    __shared__ float t_em1[256];          // e-1   at d = idx-128
    __shared__ float t_eg [256];          // e*g   (zero for |d|>35: e==1.0f exactly)
    __shared__ float lds[4];

    // ---- build window tables once per block (d = t-128, nonzero |d|<=35) ----
    {
        const int t = threadIdx.x;        // 0..255
        const float d = (float)(t - 128);
        float em1 = 0.0f, eg = 0.0f;
        if (fabsf(d) <= 35.0f) {
            const float g = fexp2(-d * d * NK2);   // gaussian target
            const float e = fexp2(g * C2P);        // exp(10*g)
            em1 = e - 1.0f;
            eg  = e * g;
        }
        t_em1[t] = em1;
        t_eg [t] = eg;
    }
    __syncthreads();

    float acc = 0.0f;

    const int rh0 = blockIdx.x * 4 + wave;
    {
        const int r0 = rh0 >> 1;
        float kx = keypoints[r0 * 3 + 0];
        float ky = keypoints[r0 * 3 + 1];
        float kv = keypoints[r0 * 3 + 2];

        for (int rh = rh0; rh < RH_TOTAL; rh += NWAVES) {
            const float kxc = kx, kyc = ky, kvc = kv;
            const int rhn = rh + NWAVES;
            if (rhn < RH_TOTAL) {             // prefetch next keypoint triple
                const int rn = rhn >> 1;
                kx = keypoints[rn * 3 + 0];
                ky = keypoints[rn * 3 + 1];
                kv = keypoints[rn * 3 + 2];
            }

            const float mux = rintf(kxc * 2.0f);   // round half-to-even = jnp.round
            const float muy = rintf(kyc * 2.0f);
            const bool oob = (mux - RAD >= 512.0f) || (muy - RAD >= 512.0f) ||
                             (mux + RAD + 1.0f < 0.0f) || (muy + RAD + 1.0f < 0.0f);
            const bool visible = (kvc >= 0.5f);
            const float w = (visible && oob) ? 0.0f : kvc;
            if (!(w > 0.0f)) continue;             // wave-uniform zero-contribution skip
            const bool valid = visible && !oob;

            const float mu  = (rh & 1) ? muy : mux;
            const int   mui = (int)mu;
            const float* pr = pred + (size_t)rh * 512;

            // ---- bulk: 8 contiguous elems/lane, two float4 loads ----
            const float* p = pr + lane * 8;
            const float4 pa = *reinterpret_cast<const float4*>(p);
            const float4 pb = *reinterpret_cast<const float4*>(p + 4);
            const float pv[8] = {pa.x, pa.y, pa.z, pa.w, pb.x, pb.y, pb.z, pb.w};

            float S = 0.0f, R = 0.0f;   // R accumulates Tp - Pd = sum(eg) - sum(em1*p) - sum(p)
            #pragma unroll
            for (int u = 0; u < 8; ++u) {
                S += fexp2(C2P * pv[u]);
                R -= pv[u];
            }

            // ---- window: table lookups, 2 elems/lane over [ws, ws+128) ----
            float Zw = 0.0f;
            if (valid) {
                int ws = mui - 64;
                ws = ws < 0 ? 0 : (ws > 384 ? 384 : ws);
                const float pw0 = pr[ws + lane];        // L1-hot re-reads
                const float pw1 = pr[ws + 64 + lane];
                int t0 = ws + lane - mui + 128;          // in [0,255] except high clamp
                int t1 = t0 + 64;
                t0 = t0 > 255 ? 255 : t0;                // clamped entries are zero
                t1 = t1 > 255 ? 255 : t1;
                const float em10 = t_em1[t0], eg0 = t_eg[t0];
                const float em11 = t_em1[t1], eg1 = t_eg[t1];
                Zw = em10 + em11;
                R += (eg0 - em10 * pw0) + (eg1 - em11 * pw1);
            }

            // ---- wave reduction: 3 scalars ----
            #pragma unroll
            for (int off = 1; off < 64; off <<= 1) {
                S  += __shfl_xor(S,  off, 64);
                Zw += __shfl_xor(Zw, off, 64);
                R  += __shfl_xor(R,  off, 64);
            }

            const float Z = 512.0f + Zw;        // far-field e == 1.0f exactly
            const float loss = 10.0f * R / Z + (__log2f(S) - __log2f(Z)) * LN2f;
            acc += w * loss;
        }
    }

    acc *= (1.0f / (512.0f * 133.0f));
    if (lane == 0) lds[wave] = acc;
    __syncthreads();
    if (threadIdx.x == 0)
        partials[blockIdx.x] = lds[0] + lds[1] + lds[2] + lds[3];
}

__global__ __launch_bounds__(256) void rtmcc_reduce_kernel(
    const float* __restrict__ partials, float* __restrict__ out)
{
    __shared__ float lds[4];
    float s = 0.0f;
    for (int i = threadIdx.x; i < NBLOCKS; i += 256) s += partials[i];
    #pragma unroll
    for (int off = 1; off < 64; off <<= 1) s += __shfl_xor(s, off, 64);
    if ((threadIdx.x & 63) == 0) lds[threadIdx.x >> 6] = s;
    __syncthreads();
    if (threadIdx.x == 0) out[0] = lds[0] + lds[1] + lds[2] + lds[3];
}

extern "C" void kernel_launch(void* const* d_in, const int* in_sizes, int n_in,
                              void* d_out, int out_size, void* d_ws, size_t ws_size,
                              hipStream_t stream) {
    const float* pred = (const float*)d_in[0];   // (256,133,1024) fp32
    const float* kpts = (const float*)d_in[1];   // (256,133,3) fp32
    float* out = (float*)d_out;
    float* partials = (float*)d_ws;

    rtmcc_partial_kernel<<<NBLOCKS, 256, 0, stream>>>(pred, kpts, partials);
    rtmcc_reduce_kernel<<<1, 256, 0, stream>>>(partials, out);
}